// Round 7
// baseline (109.411 us; speedup 1.0000x reference)
//
#include <hip/hip_runtime.h>

// Retention forward, chunkwise-linear, 3 wide-shallow stream-ordered kernels.
//   p1: U_c[e][d] = sum_j lam^(C-j) K[j][d] V[j][e]  (MFMA, chunks 0..30) -> bf16  [r0 verbatim]
//   p2: linear scan S_c = lamC*S_{c-1} + U_{c-1} — VECTORIZED u16x8 (16B/lane,
//       G13) + fully unrolled independent loads (no serial latency chain).
//       r0's p2 was 2B/lane scalar + one-ahead prefetch = ~32 serial L3 latencies.
//   p3: intra + cross (r0 verbatim champion: 3-segment LDS, 3 barriers).
// Measured design rules:
//   - grid.sync ~430us @1024 blocks — never. Cross-block flag/spin sync: 3x
//     regression, MfmaUtil 0.4% (r2) — never. Quadratic 31-term U re-scan — never.
//   - producer restructures neutral-to-negative: r1 depth-4 (+1), r4 e-split (+2),
//     r5 depth-2+relay (+5, scatter stores), r3 extra boundary (+7), r6 bundled
//     p2-unroll+p3-4seg (+3, attribution lost). r0 frame is the champion.
//   - reset fill (256MiB, ~41.5us, in timed region) evicts L3 every iter: inputs
//     HBM-cold; workspace written post-fill is L3-hot.
//   - bf16 intermediates fine: threshold 4.46, measured absmax 1.0.
//   - ONLY p2 changed this round (clean A/B vs 104.2 champion).

#define S_LEN 2048
#define DHEAD 64
#define CHUNK 64
#define NC    32
#define BH    32
#define LDK   72

typedef float  f32x4  __attribute__((ext_vector_type(4)));
typedef short  bf16x8 __attribute__((ext_vector_type(8)));
typedef unsigned short u16x8 __attribute__((ext_vector_type(8)));
typedef unsigned short u16x4 __attribute__((ext_vector_type(4)));

static __device__ __forceinline__ unsigned short f2bf(float f) {
    unsigned int u = __float_as_uint(f);
    u += 0x7FFFu + ((u >> 16) & 1u);
    return (unsigned short)(u >> 16);
}
static __device__ __forceinline__ float bf2f(unsigned short h) {
    return __uint_as_float((unsigned int)h << 16);
}

// ---------------- Phase 1: per-chunk KV summaries (U^T [e][d] bf16) ----------------
__global__ __launch_bounds__(256)
void ret_p1(const float* __restrict__ kg, const float* __restrict__ vg,
            unsigned short* __restrict__ Ug) {
    const int c  = (int)blockIdx.x, bh = (int)blockIdx.y, h = bh & 15;
    const int tid = (int)threadIdx.x;
    const int wv = tid >> 6, ln = tid & 63, quad = ln >> 4, lnlo = ln & 15;
    const float sh = log2f(1.0f - exp2f(-5.0f - (float)h));   // < 0

    __shared__ __align__(16) unsigned short Kt[CHUNK * LDK];  // lam-weighted K^T [d][j]
    __shared__ __align__(16) unsigned short Vt[CHUNK * LDK];  // V^T [e][j]

    const size_t cb = (size_t)bh * S_LEN * DHEAD + (size_t)c * CHUNK * DHEAD;
    const float* kp = kg + cb;
    const float* vp = vg + cb;

#pragma unroll
    for (int i = 0; i < 2; ++i) {
        const int pos0 = wv * 8 + i * 32;
        const float* pK = kp + (size_t)pos0 * DHEAD + ln;
        const float* pV = vp + (size_t)pos0 * DHEAD + ln;
        u16x8 tk, tv;
#pragma unroll
        for (int j = 0; j < 8; ++j) {
            const float w = exp2f(sh * (float)(CHUNK - pos0 - j));  // lam^(C - j_local)
            tk[j] = f2bf(pK[(size_t)j * DHEAD] * w);
            tv[j] = f2bf(pV[(size_t)j * DHEAD]);
        }
        *(u16x8*)&Kt[ln * LDK + pos0] = tk;
        *(u16x8*)&Vt[ln * LDK + pos0] = tv;
    }
    __syncthreads();

    bf16x8 aK[2];
#pragma unroll
    for (int ks = 0; ks < 2; ++ks)
        aK[ks] = *(const bf16x8*)&Kt[(wv * 16 + lnlo) * LDK + ks * 32 + quad * 8];

    unsigned short* up = Ug + ((size_t)(bh * NC + c) << 12);
#pragma unroll
    for (int nt = 0; nt < 4; ++nt) {
        f32x4 acc = (f32x4){0.f, 0.f, 0.f, 0.f};
#pragma unroll
        for (int ks = 0; ks < 2; ++ks) {
            const bf16x8 bv = *(const bf16x8*)&Vt[(nt * 16 + lnlo) * LDK + ks * 32 + quad * 8];
            acc = __builtin_amdgcn_mfma_f32_16x16x32_bf16(aK[ks], bv, acc, 0, 0, 0);
        }
        // U^T[e][d]: e = nt*16+lnlo, d = wv*16+quad*4+r  (8B store per lane)
        u16x4 w;
#pragma unroll
        for (int r = 0; r < 4; ++r) w[r] = f2bf(acc[r]);
        *(u16x4*)&up[(nt * 16 + lnlo) * 64 + wv * 16 + quad * 4] = w;
    }
}

// ---------------- Phase 2: linear scan, vectorized u16x8 + full unroll ----------------
// Each thread owns 8 consecutive elements (16B/lane loads AND stores, G13).
// 31 tile loads are independent compile-time offsets (bulk-issued, L3-hot);
// the only dependence is the 8-wide register FMA chain (~50ns).
// grid (8, 32) x 64 threads = 256 blocks (1 wave/CU, all CUs covered).
__global__ __launch_bounds__(64)
void ret_p2(const unsigned short* __restrict__ Ug, unsigned short* __restrict__ Sg) {
    const int seg = (int)blockIdx.x, bh = (int)blockIdx.y, h = bh & 15;
    const int ln = (int)threadIdx.x;
    const float sh   = log2f(1.0f - exp2f(-5.0f - (float)h));
    const float lamC = exp2f(sh * (float)CHUNK);
    const int elem = seg * 512 + ln * 8;   // 8 segs x 64 lanes x 8 elems = 4096

    const unsigned short* up = Ug + ((size_t)(bh * NC) << 12) + elem;
    unsigned short*       sp = Sg + ((size_t)(bh * NC) << 12) + elem;

    float S[8];
#pragma unroll
    for (int i = 0; i < 8; ++i) S[i] = 0.f;

#pragma unroll
    for (int c = 0; c < NC; ++c) {
        u16x8 w;
#pragma unroll
        for (int i = 0; i < 8; ++i) w[i] = f2bf(S[i]);
        *(u16x8*)(sp + ((size_t)c << 12)) = w;          // S_c = prefix before chunk c
        if (c < NC - 1) {                               // U_31 never produced/needed
            const u16x8 u = *(const u16x8*)(up + ((size_t)c << 12));
#pragma unroll
            for (int i = 0; i < 8; ++i) S[i] = lamC * S[i] + bf2f(u[i]);
        }
    }
}

// ---------------- Phase 3: intra + cross (r0 champion, verbatim) ----------------
__global__ __launch_bounds__(256)
void ret_p3(const float* __restrict__ qg, const float* __restrict__ kg,
            const float* __restrict__ vg, const unsigned short* __restrict__ Sg,
            float* __restrict__ og) {
    const int c  = (int)blockIdx.x, bh = (int)blockIdx.y, h = bh & 15;
    const int tid = (int)threadIdx.x;
    const int wv = tid >> 6, ln = tid & 63, quad = ln >> 4, lnlo = ln & 15;
    const float sh    = log2f(1.0f - exp2f(-5.0f - (float)h));
    const float scale = 0.125f;

    __shared__ __align__(16) unsigned short smem[3 * CHUNK * LDK];
    unsigned short* const Ks  = smem;                   // K [pos][d]
    unsigned short* const Vt  = smem + CHUNK * LDK;     // V^T [e][pos]
    unsigned short* const ShL = smem + 2 * CHUNK * LDK; // S^T [e][d]; reused as Ws

    const size_t cb = (size_t)bh * S_LEN * DHEAD + (size_t)c * CHUNK * DHEAD;
    const float* qp = qg + cb;
    const float* kp = kg + cb;
    const float* vp = vg + cb;
    float*       op = og + cb;

    // ---- stage K [pos][d] ----
    {
        const int kr = tid >> 2, kc0 = (tid & 3) * 16;
        const float* p = kp + (size_t)kr * DHEAD + kc0;
        const f32x4 x0 = *(const f32x4*)(p + 0);
        const f32x4 x1 = *(const f32x4*)(p + 4);
        const f32x4 x2 = *(const f32x4*)(p + 8);
        const f32x4 x3 = *(const f32x4*)(p + 12);
        u16x8 w0, w1;
        w0[0]=f2bf(x0[0]); w0[1]=f2bf(x0[1]); w0[2]=f2bf(x0[2]); w0[3]=f2bf(x0[3]);
        w0[4]=f2bf(x1[0]); w0[5]=f2bf(x1[1]); w0[6]=f2bf(x1[2]); w0[7]=f2bf(x1[3]);
        w1[0]=f2bf(x2[0]); w1[1]=f2bf(x2[1]); w1[2]=f2bf(x2[2]); w1[3]=f2bf(x2[3]);
        w1[4]=f2bf(x3[0]); w1[5]=f2bf(x3[1]); w1[6]=f2bf(x3[2]); w1[7]=f2bf(x3[3]);
        *(u16x8*)&Ks[kr * LDK + kc0]     = w0;
        *(u16x8*)&Ks[kr * LDK + kc0 + 8] = w1;
    }
    // ---- stage V^T [e][pos] ----
#pragma unroll
    for (int i = 0; i < 2; ++i) {
        const int pos0 = wv * 8 + i * 32;
        const float* p = vp + (size_t)pos0 * DHEAD + ln;
        u16x8 t;
#pragma unroll
        for (int j = 0; j < 8; ++j) t[j] = f2bf(p[(size_t)j * DHEAD]);
        *(u16x8*)&Vt[ln * LDK + pos0] = t;
    }
    // ---- stage S^T chunk (8 KB bf16, straight coalesced copy) ----
    {
        const size_t sb = ((size_t)(bh * NC + c) << 12) + (size_t)tid * 16;
        const int r = tid >> 2, ccol = (tid & 3) * 16;
        *(u16x8*)&ShL[r * LDK + ccol]     = *(const u16x8*)(Sg + sb);
        *(u16x8*)&ShL[r * LDK + ccol + 8] = *(const u16x8*)(Sg + sb + 8);
    }

    // ---- Q A-fragments ----
    bf16x8 aQ[2];
    {
        const float* qrow = qp + (size_t)(wv * 16 + lnlo) * DHEAD;
#pragma unroll
        for (int ks = 0; ks < 2; ++ks) {
            const float* p = qrow + ks * 32 + quad * 8;
            bf16x8 a;
#pragma unroll
            for (int j = 0; j < 8; ++j) a[j] = (short)f2bf(p[j]);
            aQ[ks] = a;
        }
    }
    float rf[4];
#pragma unroll
    for (int r = 0; r < 4; ++r) rf[r] = exp2f((float)(wv * 16 + quad * 4 + r) * sh);

    __syncthreads();

    // ---- cross: o = Q.S ----
    f32x4 o[4];
#pragma unroll
    for (int nt = 0; nt < 4; ++nt) {
        f32x4 a = (f32x4){0.f, 0.f, 0.f, 0.f};
#pragma unroll
        for (int ks = 0; ks < 2; ++ks) {
            const bf16x8 bs = *(const bf16x8*)&ShL[(nt * 16 + lnlo) * LDK + ks * 32 + quad * 8];
            a = __builtin_amdgcn_mfma_f32_16x16x32_bf16(aQ[ks], bs, a, 0, 0, 0);
        }
        o[nt] = a;
    }

    // ---- intra scores ----
    f32x4 acc[4];
#pragma unroll
    for (int nt = 0; nt < 4; ++nt) {
        f32x4 a = (f32x4){0.f, 0.f, 0.f, 0.f};
#pragma unroll
        for (int ks = 0; ks < 2; ++ks) {
            const bf16x8 bk = *(const bf16x8*)&Ks[(nt * 16 + lnlo) * LDK + ks * 32 + quad * 8];
            a = __builtin_amdgcn_mfma_f32_16x16x32_bf16(aQ[ks], bk, a, 0, 0, 0);
        }
        acc[nt] = a;
    }

    // scale cross by scale * lam^(i_local)
#pragma unroll
    for (int nt = 0; nt < 4; ++nt)
#pragma unroll
        for (int r = 0; r < 4; ++r) o[nt][r] *= rf[r] * scale;

    __syncthreads();   // all waves done reading ShL before it becomes Ws

    // ---- decay*scale*causal; C-layout -> A-layout via LDS ----
#pragma unroll
    for (int nt = 0; nt < 4; ++nt) {
        const int jn = nt * 16 + lnlo;
        const float cf = scale * exp2f(-(float)jn * sh);
#pragma unroll
        for (int r = 0; r < 4; ++r) {
            const int ri = wv * 16 + quad * 4 + r;
            float wgt = acc[nt][r] * rf[r] * cf;
            if (ri < jn) wgt = 0.0f;
            ShL[ri * LDK + jn] = f2bf(wgt);
        }
    }
    const bf16x8 aW0 = *(const bf16x8*)&ShL[(wv * 16 + lnlo) * LDK + quad * 8];
    const bf16x8 aW1 = *(const bf16x8*)&ShL[(wv * 16 + lnlo) * LDK + 32 + quad * 8];

    // ---- O += P V ----
#pragma unroll
    for (int nt = 0; nt < 4; ++nt) {
        const bf16x8 bv0 = *(const bf16x8*)&Vt[(nt * 16 + lnlo) * LDK + quad * 8];
        const bf16x8 bv1 = *(const bf16x8*)&Vt[(nt * 16 + lnlo) * LDK + 32 + quad * 8];
        o[nt] = __builtin_amdgcn_mfma_f32_16x16x32_bf16(aW0, bv0, o[nt], 0, 0, 0);
        o[nt] = __builtin_amdgcn_mfma_f32_16x16x32_bf16(aW1, bv1, o[nt], 0, 0, 0);
    }

    // ---- epilogue: bounce through LDS (Ks/Vt dead) -> coalesced dwordx4 ----
    __syncthreads();   // all waves done with Ks/Vt MFMAs before overlay
    float* const Of = (float*)smem;   // 64 x 68 fp32 = 17408 B (< Ks+Vt = 18432 B)
#pragma unroll
    for (int nt = 0; nt < 4; ++nt)
#pragma unroll
        for (int r = 0; r < 4; ++r)
            Of[(wv * 16 + quad * 4 + r) * 68 + nt * 16 + lnlo] = o[nt][r];
    // rows [wv*16, wv*16+16) written and read by the same wave -> no barrier needed
    {
        const int row = tid >> 2, col0 = (tid & 3) * 16;
        const float* src = &Of[row * 68 + col0];
        float* dst = op + (size_t)row * DHEAD + col0;
        *(f32x4*)(dst + 0)  = *(const f32x4*)(src + 0);
        *(f32x4*)(dst + 4)  = *(const f32x4*)(src + 4);
        *(f32x4*)(dst + 8)  = *(const f32x4*)(src + 8);
        *(f32x4*)(dst + 12) = *(const f32x4*)(src + 12);
    }
}

extern "C" void kernel_launch(void* const* d_in, const int* in_sizes, int n_in,
                              void* d_out, int out_size, void* d_ws, size_t ws_size,
                              hipStream_t stream) {
    (void)in_sizes; (void)n_in; (void)out_size; (void)ws_size;
    const float* q = (const float*)d_in[0];
    const float* k = (const float*)d_in[1];
    const float* v = (const float*)d_in[2];
    float* o  = (float*)d_out;
    unsigned short* Ug = (unsigned short*)d_ws;                                        // 8 MB bf16
    unsigned short* Sg = (unsigned short*)((char*)d_ws + (size_t)BH * NC * 4096 * 2);  // 8 MB bf16

    dim3 blk(256, 1, 1);
    ret_p1<<<dim3(NC - 1, BH, 1), blk, 0, stream>>>(k, v, Ug);   // U_31 never consumed
    ret_p2<<<dim3(8, BH, 1), dim3(64, 1, 1), 0, stream>>>(Ug, Sg);
    ret_p3<<<dim3(NC, BH, 1), blk, 0, stream>>>(q, k, v, Sg, o);
}

// Round 8
// 104.748 us; speedup vs baseline: 1.0445x; 1.0445x over previous
//
#include <hip/hip_runtime.h>

// Retention forward, chunkwise-linear, 3 stream-ordered kernels.
// ===== CHAMPION (r0 verbatim): measured 104.9 us (prior session) and 104.2 us (r0).
// Seven structural variants (r1-r7) all landed 105.6-111.2 (noise-to-regression):
//   r1 fused producer depth-4 (+1.4), r2 flag-sync fusion (+137, MfmaUtil 0.4%),
//   r3 4-dispatch wide-shallow (+7.0), r4 e-split producer (+2.3),
//   r5 depth-2 + V-relay scatter (+4.9), r6 p2-unroll + p3-4seg (+3.3),
//   r7 p2 u16x8 vectorized (+5.2). End-to-end noise ~±3us (fill jitters ±3%);
//   sub-3% deltas unverifiable. Plateau: ~41.5us harness fill (81% HBM peak,
//   fixed) + ~63us kernel region (~27us BW floor + 2 boundaries ~13us + ramps).
//   p1: U_c[d][e] = sum_j lam^(C-j) K[j][d] V[j][e]   (MFMA, chunks 0..30) -> bf16
//   p2: S_c = lamC * S_{c-1} + U_{c-1}  (linear elementwise scan) -> bf16 S
//   p3: O = intra-chunk + scale*lam^(i_local) * Q.S
// Design rules (measured): grid.sync ~430us @1024 blocks — never. Per-block
// prefix re-scan = quadratic U traffic (+45us) — never. Cross-block flag/spin
// sync — never (r2). bf16 intermediates: threshold 4.46, measured absmax 1.0.

#define S_LEN 2048
#define DHEAD 64
#define CHUNK 64
#define NC    32
#define BH    32
#define LDK   72

typedef float  f32x4  __attribute__((ext_vector_type(4)));
typedef short  bf16x8 __attribute__((ext_vector_type(8)));
typedef unsigned short u16x8 __attribute__((ext_vector_type(8)));
typedef unsigned short u16x4 __attribute__((ext_vector_type(4)));

static __device__ __forceinline__ unsigned short f2bf(float f) {
    unsigned int u = __float_as_uint(f);
    u += 0x7FFFu + ((u >> 16) & 1u);
    return (unsigned short)(u >> 16);
}
static __device__ __forceinline__ float bf2f(unsigned short h) {
    return __uint_as_float((unsigned int)h << 16);
}

// ---------------- Phase 1: per-chunk KV summaries (U^T [e][d] bf16) ----------------
__global__ __launch_bounds__(256)
void ret_p1(const float* __restrict__ kg, const float* __restrict__ vg,
            unsigned short* __restrict__ Ug) {
    const int c  = (int)blockIdx.x, bh = (int)blockIdx.y, h = bh & 15;
    const int tid = (int)threadIdx.x;
    const int wv = tid >> 6, ln = tid & 63, quad = ln >> 4, lnlo = ln & 15;
    const float sh = log2f(1.0f - exp2f(-5.0f - (float)h));   // < 0

    __shared__ __align__(16) unsigned short Kt[CHUNK * LDK];  // lam-weighted K^T [d][j]
    __shared__ __align__(16) unsigned short Vt[CHUNK * LDK];  // V^T [e][j]

    const size_t cb = (size_t)bh * S_LEN * DHEAD + (size_t)c * CHUNK * DHEAD;
    const float* kp = kg + cb;
    const float* vp = vg + cb;

#pragma unroll
    for (int i = 0; i < 2; ++i) {
        const int pos0 = wv * 8 + i * 32;
        const float* pK = kp + (size_t)pos0 * DHEAD + ln;
        const float* pV = vp + (size_t)pos0 * DHEAD + ln;
        u16x8 tk, tv;
#pragma unroll
        for (int j = 0; j < 8; ++j) {
            const float w = exp2f(sh * (float)(CHUNK - pos0 - j));  // lam^(C - j_local)
            tk[j] = f2bf(pK[(size_t)j * DHEAD] * w);
            tv[j] = f2bf(pV[(size_t)j * DHEAD]);
        }
        *(u16x8*)&Kt[ln * LDK + pos0] = tk;
        *(u16x8*)&Vt[ln * LDK + pos0] = tv;
    }
    __syncthreads();

    bf16x8 aK[2];
#pragma unroll
    for (int ks = 0; ks < 2; ++ks)
        aK[ks] = *(const bf16x8*)&Kt[(wv * 16 + lnlo) * LDK + ks * 32 + quad * 8];

    unsigned short* up = Ug + ((size_t)(bh * NC + c) << 12);
#pragma unroll
    for (int nt = 0; nt < 4; ++nt) {
        f32x4 acc = (f32x4){0.f, 0.f, 0.f, 0.f};
#pragma unroll
        for (int ks = 0; ks < 2; ++ks) {
            const bf16x8 bv = *(const bf16x8*)&Vt[(nt * 16 + lnlo) * LDK + ks * 32 + quad * 8];
            acc = __builtin_amdgcn_mfma_f32_16x16x32_bf16(aK[ks], bv, acc, 0, 0, 0);
        }
        // U^T[e][d]: e = nt*16+lnlo, d = wv*16+quad*4+r  (8B store per lane)
        u16x4 w;
#pragma unroll
        for (int r = 0; r < 4; ++r) w[r] = f2bf(acc[r]);
        *(u16x4*)&up[(nt * 16 + lnlo) * 64 + wv * 16 + quad * 4] = w;
    }
}

// ---------------- Phase 2: linear scan (bf16 U in, bf16 S out) ----------------
__global__ __launch_bounds__(256)
void ret_p2(const unsigned short* __restrict__ Ug, unsigned short* __restrict__ Sg) {
    const int eb = (int)blockIdx.x, bh = (int)blockIdx.y, h = bh & 15;
    const float sh   = log2f(1.0f - exp2f(-5.0f - (float)h));
    const float lamC = exp2f(sh * (float)CHUNK);
    const int elem = eb * 256 + (int)threadIdx.x;

    const unsigned short* up = Ug + ((size_t)(bh * NC) << 12) + elem;
    unsigned short*       sp = Sg + ((size_t)(bh * NC) << 12) + elem;

    float S = 0.0f;
    float u = bf2f(up[0]);
    for (int c = 0; c < NC; ++c) {
        const float un = (c + 1 < NC - 1) ? bf2f(up[(size_t)(c + 1) << 12]) : 0.0f;  // U_31 unused
        sp[(size_t)c << 12] = f2bf(S);
        S = lamC * S + u;
        u = un;
    }
}

// ---------------- Phase 3: intra + cross ----------------
__global__ __launch_bounds__(256)
void ret_p3(const float* __restrict__ qg, const float* __restrict__ kg,
            const float* __restrict__ vg, const unsigned short* __restrict__ Sg,
            float* __restrict__ og) {
    const int c  = (int)blockIdx.x, bh = (int)blockIdx.y, h = bh & 15;
    const int tid = (int)threadIdx.x;
    const int wv = tid >> 6, ln = tid & 63, quad = ln >> 4, lnlo = ln & 15;
    const float sh    = log2f(1.0f - exp2f(-5.0f - (float)h));
    const float scale = 0.125f;

    __shared__ __align__(16) unsigned short Ks[CHUNK * LDK];   // K [pos][d]
    __shared__ __align__(16) unsigned short Vt[CHUNK * LDK];   // V^T [e][pos]
    __shared__ __align__(16) unsigned short ShL[CHUNK * LDK];  // S^T [e][d]; reused as Ws

    const size_t cb = (size_t)bh * S_LEN * DHEAD + (size_t)c * CHUNK * DHEAD;
    const float* qp = qg + cb;
    const float* kp = kg + cb;
    const float* vp = vg + cb;
    float*       op = og + cb;

    // ---- stage K [pos][d] ----
    {
        const int kr = tid >> 2, kc0 = (tid & 3) * 16;
        const float* p = kp + (size_t)kr * DHEAD + kc0;
        const f32x4 x0 = *(const f32x4*)(p + 0);
        const f32x4 x1 = *(const f32x4*)(p + 4);
        const f32x4 x2 = *(const f32x4*)(p + 8);
        const f32x4 x3 = *(const f32x4*)(p + 12);
        u16x8 w0, w1;
        w0[0]=f2bf(x0[0]); w0[1]=f2bf(x0[1]); w0[2]=f2bf(x0[2]); w0[3]=f2bf(x0[3]);
        w0[4]=f2bf(x1[0]); w0[5]=f2bf(x1[1]); w0[6]=f2bf(x1[2]); w0[7]=f2bf(x1[3]);
        w1[0]=f2bf(x2[0]); w1[1]=f2bf(x2[1]); w1[2]=f2bf(x2[2]); w1[3]=f2bf(x2[3]);
        w1[4]=f2bf(x3[0]); w1[5]=f2bf(x3[1]); w1[6]=f2bf(x3[2]); w1[7]=f2bf(x3[3]);
        *(u16x8*)&Ks[kr * LDK + kc0]     = w0;
        *(u16x8*)&Ks[kr * LDK + kc0 + 8] = w1;
    }
    // ---- stage V^T [e][pos] ----
#pragma unroll
    for (int i = 0; i < 2; ++i) {
        const int pos0 = wv * 8 + i * 32;
        const float* p = vp + (size_t)pos0 * DHEAD + ln;
        u16x8 t;
#pragma unroll
        for (int j = 0; j < 8; ++j) t[j] = f2bf(p[(size_t)j * DHEAD]);
        *(u16x8*)&Vt[ln * LDK + pos0] = t;
    }
    // ---- stage S^T chunk (8 KB bf16, straight coalesced copy) ----
    {
        const size_t sb = ((size_t)(bh * NC + c) << 12) + (size_t)tid * 16;
        const int r = tid >> 2, ccol = (tid & 3) * 16;
        *(u16x8*)&ShL[r * LDK + ccol]     = *(const u16x8*)(Sg + sb);
        *(u16x8*)&ShL[r * LDK + ccol + 8] = *(const u16x8*)(Sg + sb + 8);
    }

    // ---- Q A-fragments ----
    bf16x8 aQ[2];
    {
        const float* qrow = qp + (size_t)(wv * 16 + lnlo) * DHEAD;
#pragma unroll
        for (int ks = 0; ks < 2; ++ks) {
            const float* p = qrow + ks * 32 + quad * 8;
            bf16x8 a;
#pragma unroll
            for (int j = 0; j < 8; ++j) a[j] = (short)f2bf(p[j]);
            aQ[ks] = a;
        }
    }
    float rf[4];
#pragma unroll
    for (int r = 0; r < 4; ++r) rf[r] = exp2f((float)(wv * 16 + quad * 4 + r) * sh);

    __syncthreads();

    // ---- cross: o = Q.S ----
    f32x4 o[4];
#pragma unroll
    for (int nt = 0; nt < 4; ++nt) {
        f32x4 a = (f32x4){0.f, 0.f, 0.f, 0.f};
#pragma unroll
        for (int ks = 0; ks < 2; ++ks) {
            const bf16x8 bs = *(const bf16x8*)&ShL[(nt * 16 + lnlo) * LDK + ks * 32 + quad * 8];
            a = __builtin_amdgcn_mfma_f32_16x16x32_bf16(aQ[ks], bs, a, 0, 0, 0);
        }
        o[nt] = a;
    }

    // ---- intra scores ----
    f32x4 acc[4];
#pragma unroll
    for (int nt = 0; nt < 4; ++nt) {
        f32x4 a = (f32x4){0.f, 0.f, 0.f, 0.f};
#pragma unroll
        for (int ks = 0; ks < 2; ++ks) {
            const bf16x8 bk = *(const bf16x8*)&Ks[(nt * 16 + lnlo) * LDK + ks * 32 + quad * 8];
            a = __builtin_amdgcn_mfma_f32_16x16x32_bf16(aQ[ks], bk, a, 0, 0, 0);
        }
        acc[nt] = a;
    }

    // scale cross by scale * lam^(i_local)
#pragma unroll
    for (int nt = 0; nt < 4; ++nt)
#pragma unroll
        for (int r = 0; r < 4; ++r) o[nt][r] *= rf[r] * scale;

    __syncthreads();   // all waves done reading ShL before it becomes Ws

    // ---- decay*scale*causal; C-layout -> A-layout via LDS ----
#pragma unroll
    for (int nt = 0; nt < 4; ++nt) {
        const int jn = nt * 16 + lnlo;
        const float cf = scale * exp2f(-(float)jn * sh);
#pragma unroll
        for (int r = 0; r < 4; ++r) {
            const int ri = wv * 16 + quad * 4 + r;
            float wgt = acc[nt][r] * rf[r] * cf;
            if (ri < jn) wgt = 0.0f;
            ShL[ri * LDK + jn] = f2bf(wgt);
        }
    }
    const bf16x8 aW0 = *(const bf16x8*)&ShL[(wv * 16 + lnlo) * LDK + quad * 8];
    const bf16x8 aW1 = *(const bf16x8*)&ShL[(wv * 16 + lnlo) * LDK + 32 + quad * 8];

    // ---- O += P V ----
#pragma unroll
    for (int nt = 0; nt < 4; ++nt) {
        const bf16x8 bv0 = *(const bf16x8*)&Vt[(nt * 16 + lnlo) * LDK + quad * 8];
        const bf16x8 bv1 = *(const bf16x8*)&Vt[(nt * 16 + lnlo) * LDK + 32 + quad * 8];
        o[nt] = __builtin_amdgcn_mfma_f32_16x16x32_bf16(aW0, bv0, o[nt], 0, 0, 0);
        o[nt] = __builtin_amdgcn_mfma_f32_16x16x32_bf16(aW1, bv1, o[nt], 0, 0, 0);
    }

    // ---- epilogue ----
#pragma unroll
    for (int nt = 0; nt < 4; ++nt)
#pragma unroll
        for (int r = 0; r < 4; ++r)
            op[(size_t)(wv * 16 + quad * 4 + r) * DHEAD + nt * 16 + lnlo] = o[nt][r];
}

extern "C" void kernel_launch(void* const* d_in, const int* in_sizes, int n_in,
                              void* d_out, int out_size, void* d_ws, size_t ws_size,
                              hipStream_t stream) {
    (void)in_sizes; (void)n_in; (void)out_size; (void)ws_size;
    const float* q = (const float*)d_in[0];
    const float* k = (const float*)d_in[1];
    const float* v = (const float*)d_in[2];
    float* o  = (float*)d_out;
    unsigned short* Ug = (unsigned short*)d_ws;                                  // 8 MB bf16
    unsigned short* Sg = (unsigned short*)((char*)d_ws + (size_t)BH * NC * 4096 * 2);  // 8 MB bf16

    dim3 blk(256, 1, 1);
    ret_p1<<<dim3(NC - 1, BH, 1), blk, 0, stream>>>(k, v, Ug);   // U_31 never consumed
    ret_p2<<<dim3(16, BH, 1), blk, 0, stream>>>(Ug, Sg);
    ret_p3<<<dim3(NC, BH, 1), blk, 0, stream>>>(q, k, v, Sg, o);
}